// Round 3
// baseline (3702.833 us; speedup 1.0000x reference)
//
#include <hip/hip_runtime.h>

#define TOKENS 4096
#define HD 2048
#define FF 8192
#define NE 8
#define NS 2

typedef __attribute__((ext_vector_type(8))) short bf16x8;
typedef __attribute__((ext_vector_type(4))) float f32x4;

__device__ __forceinline__ unsigned rnd_bf(unsigned u) {
  return u + 0x7fffu + ((u >> 16) & 1u);
}
__device__ __forceinline__ unsigned short f2bf(float f) {
  unsigned u = __builtin_bit_cast(unsigned, f);
  return (unsigned short)(rnd_bf(u) >> 16);
}

#define GLDS16(gp, lp)                                                         \
  __builtin_amdgcn_global_load_lds(                                            \
      (const __attribute__((address_space(1))) unsigned*)(const void*)(gp),    \
      (__attribute__((address_space(3))) unsigned*)(lp), 16, 0, 0)

// ---------------- cast x f32 -> bf16 ----------------
__global__ void cast_x_kernel(const float* __restrict__ x, unsigned short* __restrict__ xb) {
  const size_t i = ((size_t)blockIdx.x * 256 + threadIdx.x) * 4;
  float4 v = *(const float4*)(x + i);
  ushort4 o;
  o.x = f2bf(v.x); o.y = f2bf(v.y); o.z = f2bf(v.z); o.w = f2bf(v.w);
  *(ushort4*)(xb + i) = o;
}

// ---------------- router ----------------
__global__ void router_kernel(const float* __restrict__ x, const float* __restrict__ wg,
                              float* __restrict__ logits_out, int* __restrict__ topi,
                              float* __restrict__ topv, int* __restrict__ counts) {
  const int wave = threadIdx.x >> 6, lane = threadIdx.x & 63;
  const int t = blockIdx.x * 4 + wave;
  const float* xr = x + (size_t)t * HD;
  float acc[8];
#pragma unroll
  for (int e = 0; e < 8; ++e) acc[e] = 0.f;
  for (int d = lane; d < HD; d += 64) {
    const float xv = xr[d];
    const float4 w0 = *(const float4*)(wg + (size_t)d * 8);
    const float4 w1 = *(const float4*)(wg + (size_t)d * 8 + 4);
    acc[0] += xv * w0.x; acc[1] += xv * w0.y; acc[2] += xv * w0.z; acc[3] += xv * w0.w;
    acc[4] += xv * w1.x; acc[5] += xv * w1.y; acc[6] += xv * w1.z; acc[7] += xv * w1.w;
  }
#pragma unroll
  for (int e = 0; e < 8; ++e) {
#pragma unroll
    for (int off = 32; off > 0; off >>= 1) acc[e] += __shfl_xor(acc[e], off);
  }
  if (lane == 0) {
    *(float4*)(logits_out + (size_t)t * 8)     = make_float4(acc[0], acc[1], acc[2], acc[3]);
    *(float4*)(logits_out + (size_t)t * 8 + 4) = make_float4(acc[4], acc[5], acc[6], acc[7]);
    float mx = acc[0];
#pragma unroll
    for (int e = 1; e < 8; ++e) mx = fmaxf(mx, acc[e]);
    float p[8], s = 0.f;
#pragma unroll
    for (int e = 0; e < 8; ++e) { p[e] = expf(acc[e] - mx); s += p[e]; }
    const float inv = 1.f / s;
    int i1 = 0;
#pragma unroll
    for (int e = 1; e < 8; ++e) if (acc[e] > acc[i1]) i1 = e;
    int i2 = (i1 == 0) ? 1 : 0;
#pragma unroll
    for (int e = 0; e < 8; ++e) if (e != i1 && acc[e] > acc[i2]) i2 = e;
    topi[2 * t]     = i1; topv[2 * t]     = p[i1] * inv;
    topi[2 * t + 1] = i2; topv[2 * t + 1] = p[i2] * inv;
    atomicAdd(&counts[i1], 1);
    atomicAdd(&counts[i2], 1);
  }
}

__global__ void offs_kernel(const int* __restrict__ counts, int* __restrict__ offs,
                            int* __restrict__ cursors) {
  if (threadIdx.x == 0) {
    int r = 0;
    for (int e = 0; e < NE; ++e) { offs[e] = r; cursors[e] = r; r += counts[e]; }
  }
}

__global__ void gather_kernel(const unsigned short* __restrict__ xb,
                              const int* __restrict__ topi, const float* __restrict__ topv,
                              int* __restrict__ cursors, unsigned short* __restrict__ xg,
                              int* __restrict__ row_token, float* __restrict__ row_gate) {
  const int wave = threadIdx.x >> 6, lane = threadIdx.x & 63;
  const int t = blockIdx.x * 4 + wave;
  const uint4* src = (const uint4*)(xb + (size_t)t * HD);
#pragma unroll
  for (int j = 0; j < 2; ++j) {
    const int e = topi[2 * t + j];
    int pos = 0;
    if (lane == 0) {
      pos = atomicAdd(&cursors[e], 1);
      row_token[pos] = t;
      row_gate[pos] = topv[2 * t + j];
    }
    pos = __shfl(pos, 0);
    uint4* dst = (uint4*)(xg + (size_t)pos * HD);
#pragma unroll
    for (int c = lane; c < 256; c += 64) dst[c] = src[c];
  }
}

// ---------------- pack: f32 [K][N] -> bf16 B^T [N][K] ----------------
template <int K, int N>
__global__ __launch_bounds__(256) void pack_wt(const float* __restrict__ we,
                                               const float* __restrict__ ws,
                                               unsigned short* __restrict__ dstw) {
  const int e = blockIdx.z;
  const float* src = (e < NE) ? (we + (size_t)e * K * N) : (ws + (size_t)(e - NE) * K * N);
  unsigned short* dst = dstw + (size_t)e * K * N;
  const int nt = blockIdx.x * 64;
  const int kt = blockIdx.y * 64;
  __shared__ unsigned short t[64][73];
  const int tid = threadIdx.x;
  const int rr = tid >> 4, cc = (tid & 15) * 4;
#pragma unroll
  for (int i = 0; i < 4; ++i) {
    const int k = rr + i * 16;
    float4 v = *(const float4*)(src + (size_t)(kt + k) * N + nt + cc);
    t[k][cc + 0] = f2bf(v.x);
    t[k][cc + 1] = f2bf(v.y);
    t[k][cc + 2] = f2bf(v.z);
    t[k][cc + 3] = f2bf(v.w);
  }
  __syncthreads();
  const int nr = tid >> 2, kc = (tid & 3) * 16;
  unsigned u[8];
#pragma unroll
  for (int j = 0; j < 8; ++j)
    u[j] = (unsigned)t[kc + 2 * j][nr] | ((unsigned)t[kc + 2 * j + 1][nr] << 16);
  unsigned short* dp = dst + (size_t)(nt + nr) * K + kt + kc;
  uint4 v0; v0.x = u[0]; v0.y = u[1]; v0.z = u[2]; v0.w = u[3];
  uint4 v1; v1.x = u[4]; v1.y = u[5]; v1.z = u[6]; v1.w = u[7];
  *(uint4*)dp = v0;
  *(uint4*)(dp + 8) = v1;
}

// ---------------- bf16 B^T grouped GEMM ----------------
// m97 structure + both-sides XOR swizzle (pre-swizzled global source,
// linear global_load_lds dest, swizzled ds_read) + chunked XCD block swizzle.
// MODE 0: h = relu(A[M x 2048] * W1t^T + b1) -> bf16 hbuf
// MODE 1: out[token] += gate * (A[M x 8192] * W2t^T + b2)  (atomic f32)
template <int MODE>
__global__ __launch_bounds__(256) void gemm_bt(
    const unsigned short* __restrict__ Ash,   // MODE0: xb, MODE1: hbuf
    const unsigned short* __restrict__ Art,   // MODE0: xg, MODE1: hbuf
    const unsigned short* __restrict__ wt,    // packed B^T [10][N*K]
    const float* __restrict__ bE, const float* __restrict__ bS,
    unsigned short* __restrict__ hout, float* __restrict__ out,
    const int* __restrict__ counts, const int* __restrict__ offs,
    const int* __restrict__ row_token, const float* __restrict__ row_gate) {
  constexpr int K = (MODE == 0) ? HD : FF;
  constexpr int N = (MODE == 0) ? FF : HD;
  constexpr int NBLK = N / 128;               // 64 or 16
  constexpr int NSH = (MODE == 0) ? 6 : 4;    // log2(NBLK)
  constexpr int NWG = NBLK * 32;              // xy blocks per expert (%8==0)

  const int e = blockIdx.z;
  int M;
  const unsigned short* A;
  const float* bias;
  int hbase = 0;
  const int* tok = nullptr;
  const float* gt = nullptr;

  if (e < NE) {
    M = counts[e];
    const int off = offs[e];
    A = Art + (size_t)off * K;
    if (MODE == 1) { tok = row_token + off; gt = row_gate + off; }
    bias = bE + (size_t)e * N;
    hbase = off;
  } else {
    M = TOKENS;
    const int se = e - NE;
    hbase = 2 * TOKENS + se * TOKENS;
    if (MODE == 0) A = Ash;
    else           A = Ash + (size_t)hbase * K;
    bias = bS + (size_t)se * N;
  }
  const unsigned short* Bt = wt + (size_t)e * HD * FF;  // [N][K]

  // chunked XCD swizzle over the xy plane (NWG % 8 == 0; z offset is %8==0)
  int flat = blockIdx.x + NBLK * blockIdx.y;
  flat = (flat & 7) * (NWG >> 3) + (flat >> 3);
  const int m0 = (flat >> NSH) * 128;
  const int n0 = (flat & (NBLK - 1)) * 128;
  if (m0 >= M) return;

  __shared__ __align__(16) unsigned short As[128 * 64];
  __shared__ __align__(16) unsigned short Bs[128 * 64];

  const int tid = threadIdx.x;
  const int wv = tid >> 6;
  const int ln = tid & 63;
  const int fr = ln & 15;
  const int fq = ln >> 4;
  const int wr = (wv >> 1) * 64;
  const int wc = (wv & 1) * 64;
  const int lrow = ln >> 3;                       // 0..7
  const int lcs = ((ln & 7) ^ lrow) << 3;         // pre-swizzled ushort col

  f32x4 acc[4][4];
#pragma unroll
  for (int i = 0; i < 4; ++i)
#pragma unroll
    for (int j = 0; j < 4; ++j) acc[i][j] = (f32x4){0.f, 0.f, 0.f, 0.f};

  const unsigned short* a_base = A + (size_t)(m0 + wv * 32 + lrow) * K + lcs;
  const unsigned short* b_base = Bt + (size_t)(n0 + wv * 32 + lrow) * K + lcs;
  unsigned short* as_base = As + (wv * 32) * 64;
  unsigned short* bs_base = Bs + (wv * 32) * 64;

  const int nkt = K / 64;
  for (int kt = 0; kt < nkt; ++kt) {
    const int ko = kt * 64;
#pragma unroll
    for (int i = 0; i < 4; ++i)
      GLDS16(a_base + (size_t)(i * 8) * K + ko, as_base + (i * 8) * 64);
#pragma unroll
    for (int i = 0; i < 4; ++i)
      GLDS16(b_base + (size_t)(i * 8) * K + ko, bs_base + (i * 8) * 64);
    __syncthreads();
#pragma unroll
    for (int kk = 0; kk < 2; ++kk) {
      bf16x8 af[4], bfr[4];
#pragma unroll
      for (int mi = 0; mi < 4; ++mi) {
        const int row = wr + mi * 16 + fr;
        af[mi] = *(const bf16x8*)(As + row * 64 + ((kk * 32 + fq * 8) ^ ((row & 7) << 3)));
      }
#pragma unroll
      for (int ni = 0; ni < 4; ++ni) {
        const int col = wc + ni * 16 + fr;
        bfr[ni] = *(const bf16x8*)(Bs + col * 64 + ((kk * 32 + fq * 8) ^ ((col & 7) << 3)));
      }
#pragma unroll
      for (int mi = 0; mi < 4; ++mi)
#pragma unroll
        for (int ni = 0; ni < 4; ++ni)
          acc[mi][ni] = __builtin_amdgcn_mfma_f32_16x16x32_bf16(af[mi], bfr[ni], acc[mi][ni], 0, 0, 0);
    }
    __syncthreads();
  }

  if (MODE == 0) {
#pragma unroll
    for (int ni = 0; ni < 4; ++ni) {
      const int col = n0 + wc + ni * 16 + fr;
      const float bb = bias[col];
#pragma unroll
      for (int mi = 0; mi < 4; ++mi) {
#pragma unroll
        for (int j = 0; j < 4; ++j) {
          const int r = m0 + wr + mi * 16 + fq * 4 + j;
          if (r < M) {
            float v = acc[mi][ni][j] + bb;
            v = v > 0.f ? v : 0.f;
            hout[(size_t)(hbase + r) * FF + col] = f2bf(v);
          }
        }
      }
    }
  } else {
#pragma unroll
    for (int mi = 0; mi < 4; ++mi) {
#pragma unroll
      for (int j = 0; j < 4; ++j) {
        const int r = m0 + wr + mi * 16 + fq * 4 + j;
        if (r < M) {
          const int t = tok ? tok[r] : r;
          const float g = gt ? gt[r] : 1.f;
          float* orow = out + (size_t)t * HD + n0;
#pragma unroll
          for (int ni = 0; ni < 4; ++ni) {
            const int col = wc + ni * 16 + fr;
            atomicAdd(orow + col, g * (acc[mi][ni][j] + bias[n0 + col]));
          }
        }
      }
    }
  }
}

extern "C" void kernel_launch(void* const* d_in, const int* in_sizes, int n_in,
                              void* d_out, int out_size, void* d_ws, size_t ws_size,
                              hipStream_t stream) {
  const float* x     = (const float*)d_in[0];
  const float* ws_w1 = (const float*)d_in[1];
  const float* ws_b1 = (const float*)d_in[2];
  const float* ws_w2 = (const float*)d_in[3];
  const float* ws_b2 = (const float*)d_in[4];
  const float* we_w1 = (const float*)d_in[5];
  const float* we_b1 = (const float*)d_in[6];
  const float* we_w2 = (const float*)d_in[7];
  const float* we_b2 = (const float*)d_in[8];
  const float* wg    = (const float*)d_in[9];

  float* out = (float*)d_out;
  float* logits = out + (size_t)TOKENS * HD;

  char* ws = (char*)d_ws;
  unsigned short* wt   = (unsigned short*)ws;                   // 335,544,320 B (W1t then W2t)
  unsigned short* hbuf = (unsigned short*)(ws + 335544320);     // 268,435,456 B
  unsigned short* xb   = (unsigned short*)(ws + 603979776);     // 16,777,216 B
  unsigned short* xg   = (unsigned short*)(ws + 620756992);     // 34,078,720 B
  char* ctrl = ws + 654835712;
  int*   row_token = (int*)(ctrl);
  float* row_gate  = (float*)(ctrl + 32768);
  int*   topi      = (int*)(ctrl + 65536);
  float* topv      = (float*)(ctrl + 98304);
  int*   counts    = (int*)(ctrl + 131072);
  int*   offs      = (int*)(ctrl + 131104);
  int*   cursors   = (int*)(ctrl + 131136);

  hipMemsetAsync(out, 0, (size_t)TOKENS * HD * sizeof(float), stream);
  hipMemsetAsync(counts, 0, NE * sizeof(int), stream);

  cast_x_kernel<<<8192, 256, 0, stream>>>(x, xb);
  router_kernel<<<1024, 256, 0, stream>>>(x, wg, logits, topi, topv, counts);
  offs_kernel<<<1, 64, 0, stream>>>(counts, offs, cursors);
  gather_kernel<<<1024, 256, 0, stream>>>(xb, topi, topv, cursors, xg, row_token, row_gate);

  // pack W1 [10][2048][8192] f32 -> [10][8192][2048] bf16
  pack_wt<HD, FF><<<dim3(FF / 64, HD / 64, 10), 256, 0, stream>>>(we_w1, ws_w1, wt);
  // GEMM1: h = relu(x*W1+b1)
  gemm_bt<0><<<dim3(64, 32, 10), 256, 0, stream>>>(
      xb, xg, wt, we_b1, ws_b1, hbuf, nullptr, counts, offs, nullptr, nullptr);
  // pack W2 [10][8192][2048] f32 -> [10][2048][8192] bf16 (reuses wt)
  pack_wt<FF, HD><<<dim3(HD / 64, FF / 64, 10), 256, 0, stream>>>(we_w2, ws_w2, wt);
  // GEMM2: out += gate*(h*W2+b2)
  gemm_bt<1><<<dim3(16, 32, 10), 256, 0, stream>>>(
      hbuf, hbuf, wt, we_b2, ws_b2, nullptr, out, counts, offs, row_token, row_gate);

  (void)in_sizes; (void)n_in; (void)out_size; (void)ws_size;
}

// Round 4
// 2165.091 us; speedup vs baseline: 1.7102x; 1.7102x over previous
//
#include <hip/hip_runtime.h>

#define TOKENS 4096
#define HD 2048
#define FF 8192
#define NE 8
#define NS 2

typedef __attribute__((ext_vector_type(8))) short bf16x8;
typedef __attribute__((ext_vector_type(4))) float f32x4;

__device__ __forceinline__ unsigned rnd_bf(unsigned u) {
  return u + 0x7fffu + ((u >> 16) & 1u);
}
__device__ __forceinline__ unsigned short f2bf(float f) {
  unsigned u = __builtin_bit_cast(unsigned, f);
  return (unsigned short)(rnd_bf(u) >> 16);
}

#define GLDS16(gp, lp)                                                         \
  __builtin_amdgcn_global_load_lds(                                            \
      (const __attribute__((address_space(1))) unsigned*)(const void*)(gp),    \
      (__attribute__((address_space(3))) unsigned*)(lp), 16, 0, 0)

// ---------------- cast x f32 -> bf16 ----------------
__global__ void cast_x_kernel(const float* __restrict__ x, unsigned short* __restrict__ xb) {
  const size_t i = ((size_t)blockIdx.x * 256 + threadIdx.x) * 4;
  float4 v = *(const float4*)(x + i);
  ushort4 o;
  o.x = f2bf(v.x); o.y = f2bf(v.y); o.z = f2bf(v.z); o.w = f2bf(v.w);
  *(ushort4*)(xb + i) = o;
}

// ---------------- router ----------------
__global__ void router_kernel(const float* __restrict__ x, const float* __restrict__ wg,
                              float* __restrict__ logits_out, int* __restrict__ topi,
                              float* __restrict__ topv, int* __restrict__ counts) {
  const int wave = threadIdx.x >> 6, lane = threadIdx.x & 63;
  const int t = blockIdx.x * 4 + wave;
  const float* xr = x + (size_t)t * HD;
  float acc[8];
#pragma unroll
  for (int e = 0; e < 8; ++e) acc[e] = 0.f;
  for (int d = lane; d < HD; d += 64) {
    const float xv = xr[d];
    const float4 w0 = *(const float4*)(wg + (size_t)d * 8);
    const float4 w1 = *(const float4*)(wg + (size_t)d * 8 + 4);
    acc[0] += xv * w0.x; acc[1] += xv * w0.y; acc[2] += xv * w0.z; acc[3] += xv * w0.w;
    acc[4] += xv * w1.x; acc[5] += xv * w1.y; acc[6] += xv * w1.z; acc[7] += xv * w1.w;
  }
#pragma unroll
  for (int e = 0; e < 8; ++e) {
#pragma unroll
    for (int off = 32; off > 0; off >>= 1) acc[e] += __shfl_xor(acc[e], off);
  }
  if (lane == 0) {
    *(float4*)(logits_out + (size_t)t * 8)     = make_float4(acc[0], acc[1], acc[2], acc[3]);
    *(float4*)(logits_out + (size_t)t * 8 + 4) = make_float4(acc[4], acc[5], acc[6], acc[7]);
    float mx = acc[0];
#pragma unroll
    for (int e = 1; e < 8; ++e) mx = fmaxf(mx, acc[e]);
    float p[8], s = 0.f;
#pragma unroll
    for (int e = 0; e < 8; ++e) { p[e] = expf(acc[e] - mx); s += p[e]; }
    const float inv = 1.f / s;
    int i1 = 0;
#pragma unroll
    for (int e = 1; e < 8; ++e) if (acc[e] > acc[i1]) i1 = e;
    int i2 = (i1 == 0) ? 1 : 0;
#pragma unroll
    for (int e = 0; e < 8; ++e) if (e != i1 && acc[e] > acc[i2]) i2 = e;
    topi[2 * t]     = i1; topv[2 * t]     = p[i1] * inv;
    topi[2 * t + 1] = i2; topv[2 * t + 1] = p[i2] * inv;
    atomicAdd(&counts[i1], 1);
    atomicAdd(&counts[i2], 1);
  }
}

__global__ void offs_kernel(const int* __restrict__ counts, int* __restrict__ offs,
                            int* __restrict__ cursors) {
  if (threadIdx.x == 0) {
    int r = 0;
    for (int e = 0; e < NE; ++e) { offs[e] = r; cursors[e] = r; r += counts[e]; }
  }
}

__global__ void gather_kernel(const unsigned short* __restrict__ xb,
                              const int* __restrict__ topi, const float* __restrict__ topv,
                              int* __restrict__ cursors, unsigned short* __restrict__ xg,
                              int* __restrict__ row_token, float* __restrict__ row_gate) {
  const int wave = threadIdx.x >> 6, lane = threadIdx.x & 63;
  const int t = blockIdx.x * 4 + wave;
  const uint4* src = (const uint4*)(xb + (size_t)t * HD);
#pragma unroll
  for (int j = 0; j < 2; ++j) {
    const int e = topi[2 * t + j];
    int pos = 0;
    if (lane == 0) {
      pos = atomicAdd(&cursors[e], 1);
      row_token[pos] = t;
      row_gate[pos] = topv[2 * t + j];
    }
    pos = __shfl(pos, 0);
    uint4* dst = (uint4*)(xg + (size_t)pos * HD);
#pragma unroll
    for (int c = lane; c < 256; c += 64) dst[c] = src[c];
  }
}

// ---------------- pack: f32 [K][N] -> bf16 B^T [N][K] ----------------
template <int K, int N>
__global__ __launch_bounds__(256) void pack_wt(const float* __restrict__ we,
                                               const float* __restrict__ ws,
                                               unsigned short* __restrict__ dstw) {
  const int e = blockIdx.z;
  const float* src = (e < NE) ? (we + (size_t)e * K * N) : (ws + (size_t)(e - NE) * K * N);
  unsigned short* dst = dstw + (size_t)e * K * N;
  const int nt = blockIdx.x * 64;
  const int kt = blockIdx.y * 64;
  __shared__ unsigned short t[64][73];
  const int tid = threadIdx.x;
  const int rr = tid >> 4, cc = (tid & 15) * 4;
#pragma unroll
  for (int i = 0; i < 4; ++i) {
    const int k = rr + i * 16;
    float4 v = *(const float4*)(src + (size_t)(kt + k) * N + nt + cc);
    t[k][cc + 0] = f2bf(v.x);
    t[k][cc + 1] = f2bf(v.y);
    t[k][cc + 2] = f2bf(v.z);
    t[k][cc + 3] = f2bf(v.w);
  }
  __syncthreads();
  const int nr = tid >> 2, kc = (tid & 3) * 16;
  unsigned u[8];
#pragma unroll
  for (int j = 0; j < 8; ++j)
    u[j] = (unsigned)t[kc + 2 * j][nr] | ((unsigned)t[kc + 2 * j + 1][nr] << 16);
  unsigned short* dp = dst + (size_t)(nt + nr) * K + kt + kc;
  uint4 v0; v0.x = u[0]; v0.y = u[1]; v0.z = u[2]; v0.w = u[3];
  uint4 v1; v1.x = u[4]; v1.y = u[5]; v1.z = u[6]; v1.w = u[7];
  *(uint4*)dp = v0;
  *(uint4*)(dp + 8) = v1;
}

// ---------------- bf16 B^T grouped GEMM ----------------
// m97 structure + both-sides XOR swizzle (pre-swizzled global source,
// linear global_load_lds dest, swizzled ds_read) + chunked XCD block
// swizzle with m-FAST work mapping (uniform validity for runtime M;
// each XCD owns a narrow n-band -> B-slice L2-resident).
// MODE 0: h = relu(A[M x 2048] * W1t^T + b1) -> bf16 hbuf
// MODE 1: out[token] += gate * (A[M x 8192] * W2t^T + b2)  (atomic f32)
template <int MODE>
__global__ __launch_bounds__(256) void gemm_bt(
    const unsigned short* __restrict__ Ash,   // MODE0: xb, MODE1: hbuf
    const unsigned short* __restrict__ Art,   // MODE0: xg, MODE1: hbuf
    const unsigned short* __restrict__ wt,    // packed B^T [10][N*K]
    const float* __restrict__ bE, const float* __restrict__ bS,
    unsigned short* __restrict__ hout, float* __restrict__ out,
    const int* __restrict__ counts, const int* __restrict__ offs,
    const int* __restrict__ row_token, const float* __restrict__ row_gate) {
  constexpr int K = (MODE == 0) ? HD : FF;
  constexpr int N = (MODE == 0) ? FF : HD;
  constexpr int NBLK = N / 128;               // 64 or 16
  constexpr int NWG = NBLK * 32;              // xy blocks per expert (%8==0)

  const int e = blockIdx.z;
  int M;
  const unsigned short* A;
  const float* bias;
  int hbase = 0;
  const int* tok = nullptr;
  const float* gt = nullptr;

  if (e < NE) {
    M = counts[e];
    const int off = offs[e];
    A = Art + (size_t)off * K;
    if (MODE == 1) { tok = row_token + off; gt = row_gate + off; }
    bias = bE + (size_t)e * N;
    hbase = off;
  } else {
    M = TOKENS;
    const int se = e - NE;
    hbase = 2 * TOKENS + se * TOKENS;
    if (MODE == 0) A = Ash;
    else           A = Ash + (size_t)hbase * K;
    bias = bS + (size_t)se * N;
  }
  const unsigned short* Bt = wt + (size_t)e * HD * FF;  // [N][K]

  // chunked XCD swizzle; m is the FAST dim of the work map so that the
  // valid set {flat&31 < M/128} is uniform across every XCD chunk.
  int flat = blockIdx.x + NBLK * blockIdx.y;
  flat = (flat & 7) * (NWG >> 3) + (flat >> 3);
  const int m0 = (flat & 31) * 128;
  const int n0 = (flat >> 5) * 128;
  if (m0 >= M) return;

  __shared__ __align__(16) unsigned short As[128 * 64];
  __shared__ __align__(16) unsigned short Bs[128 * 64];

  const int tid = threadIdx.x;
  const int wv = tid >> 6;
  const int ln = tid & 63;
  const int fr = ln & 15;
  const int fq = ln >> 4;
  const int wr = (wv >> 1) * 64;
  const int wc = (wv & 1) * 64;
  const int lrow = ln >> 3;                       // 0..7
  const int lcs = ((ln & 7) ^ lrow) << 3;         // pre-swizzled ushort col

  f32x4 acc[4][4];
#pragma unroll
  for (int i = 0; i < 4; ++i)
#pragma unroll
    for (int j = 0; j < 4; ++j) acc[i][j] = (f32x4){0.f, 0.f, 0.f, 0.f};

  const unsigned short* a_base = A + (size_t)(m0 + wv * 32 + lrow) * K + lcs;
  const unsigned short* b_base = Bt + (size_t)(n0 + wv * 32 + lrow) * K + lcs;
  unsigned short* as_base = As + (wv * 32) * 64;
  unsigned short* bs_base = Bs + (wv * 32) * 64;

  const int nkt = K / 64;
  for (int kt = 0; kt < nkt; ++kt) {
    const int ko = kt * 64;
#pragma unroll
    for (int i = 0; i < 4; ++i)
      GLDS16(a_base + (size_t)(i * 8) * K + ko, as_base + (i * 8) * 64);
#pragma unroll
    for (int i = 0; i < 4; ++i)
      GLDS16(b_base + (size_t)(i * 8) * K + ko, bs_base + (i * 8) * 64);
    __syncthreads();
#pragma unroll
    for (int kk = 0; kk < 2; ++kk) {
      bf16x8 af[4], bfr[4];
#pragma unroll
      for (int mi = 0; mi < 4; ++mi) {
        const int row = wr + mi * 16 + fr;
        af[mi] = *(const bf16x8*)(As + row * 64 + ((kk * 32 + fq * 8) ^ ((row & 7) << 3)));
      }
#pragma unroll
      for (int ni = 0; ni < 4; ++ni) {
        const int col = wc + ni * 16 + fr;
        bfr[ni] = *(const bf16x8*)(Bs + col * 64 + ((kk * 32 + fq * 8) ^ ((col & 7) << 3)));
      }
#pragma unroll
      for (int mi = 0; mi < 4; ++mi)
#pragma unroll
        for (int ni = 0; ni < 4; ++ni)
          acc[mi][ni] = __builtin_amdgcn_mfma_f32_16x16x32_bf16(af[mi], bfr[ni], acc[mi][ni], 0, 0, 0);
    }
    __syncthreads();
  }

  if (MODE == 0) {
#pragma unroll
    for (int ni = 0; ni < 4; ++ni) {
      const int col = n0 + wc + ni * 16 + fr;
      const float bb = bias[col];
#pragma unroll
      for (int mi = 0; mi < 4; ++mi) {
#pragma unroll
        for (int j = 0; j < 4; ++j) {
          const int r = m0 + wr + mi * 16 + fq * 4 + j;
          if (r < M) {
            float v = acc[mi][ni][j] + bb;
            v = v > 0.f ? v : 0.f;
            hout[(size_t)(hbase + r) * FF + col] = f2bf(v);
          }
        }
      }
    }
  } else {
#pragma unroll
    for (int mi = 0; mi < 4; ++mi) {
#pragma unroll
      for (int j = 0; j < 4; ++j) {
        const int r = m0 + wr + mi * 16 + fq * 4 + j;
        if (r < M) {
          const int t = tok ? tok[r] : r;
          const float g = gt ? gt[r] : 1.f;
          float* orow = out + (size_t)t * HD + n0;
#pragma unroll
          for (int ni = 0; ni < 4; ++ni) {
            const int col = wc + ni * 16 + fr;
            atomicAdd(orow + col, g * (acc[mi][ni][j] + bias[n0 + col]));
          }
        }
      }
    }
  }
}

extern "C" void kernel_launch(void* const* d_in, const int* in_sizes, int n_in,
                              void* d_out, int out_size, void* d_ws, size_t ws_size,
                              hipStream_t stream) {
  const float* x     = (const float*)d_in[0];
  const float* ws_w1 = (const float*)d_in[1];
  const float* ws_b1 = (const float*)d_in[2];
  const float* ws_w2 = (const float*)d_in[3];
  const float* ws_b2 = (const float*)d_in[4];
  const float* we_w1 = (const float*)d_in[5];
  const float* we_b1 = (const float*)d_in[6];
  const float* we_w2 = (const float*)d_in[7];
  const float* we_b2 = (const float*)d_in[8];
  const float* wg    = (const float*)d_in[9];

  float* out = (float*)d_out;
  float* logits = out + (size_t)TOKENS * HD;

  char* ws = (char*)d_ws;
  unsigned short* wt   = (unsigned short*)ws;                   // 335,544,320 B (W1t then W2t)
  unsigned short* hbuf = (unsigned short*)(ws + 335544320);     // 268,435,456 B
  unsigned short* xb   = (unsigned short*)(ws + 603979776);     // 16,777,216 B
  unsigned short* xg   = (unsigned short*)(ws + 620756992);     // 34,078,720 B
  char* ctrl = ws + 654835712;
  int*   row_token = (int*)(ctrl);
  float* row_gate  = (float*)(ctrl + 32768);
  int*   topi      = (int*)(ctrl + 65536);
  float* topv      = (float*)(ctrl + 98304);
  int*   counts    = (int*)(ctrl + 131072);
  int*   offs      = (int*)(ctrl + 131104);
  int*   cursors   = (int*)(ctrl + 131136);

  hipMemsetAsync(out, 0, (size_t)TOKENS * HD * sizeof(float), stream);
  hipMemsetAsync(counts, 0, NE * sizeof(int), stream);

  cast_x_kernel<<<8192, 256, 0, stream>>>(x, xb);
  router_kernel<<<1024, 256, 0, stream>>>(x, wg, logits, topi, topv, counts);
  offs_kernel<<<1, 64, 0, stream>>>(counts, offs, cursors);
  gather_kernel<<<1024, 256, 0, stream>>>(xb, topi, topv, cursors, xg, row_token, row_gate);

  // pack W1 [10][2048][8192] f32 -> [10][8192][2048] bf16
  pack_wt<HD, FF><<<dim3(FF / 64, HD / 64, 10), 256, 0, stream>>>(we_w1, ws_w1, wt);
  // GEMM1: h = relu(x*W1+b1)
  gemm_bt<0><<<dim3(64, 32, 10), 256, 0, stream>>>(
      xb, xg, wt, we_b1, ws_b1, hbuf, nullptr, counts, offs, nullptr, nullptr);
  // pack W2 [10][8192][2048] f32 -> [10][2048][8192] bf16 (reuses wt)
  pack_wt<FF, HD><<<dim3(HD / 64, FF / 64, 10), 256, 0, stream>>>(we_w2, ws_w2, wt);
  // GEMM2: out += gate*(h*W2+b2)
  gemm_bt<1><<<dim3(16, 32, 10), 256, 0, stream>>>(
      hbuf, hbuf, wt, we_b2, ws_b2, nullptr, out, counts, offs, row_token, row_gate);

  (void)in_sizes; (void)n_in; (void)out_size; (void)ws_size;
}

// Round 5
// 2019.465 us; speedup vs baseline: 1.8336x; 1.0721x over previous
//
#include <hip/hip_runtime.h>

#define TOKENS 4096
#define HD 2048
#define FF 8192
#define NE 8
#define NS 2

typedef __attribute__((ext_vector_type(8))) short bf16x8;
typedef __attribute__((ext_vector_type(4))) float f32x4;

__device__ __forceinline__ unsigned rnd_bf(unsigned u) {
  return u + 0x7fffu + ((u >> 16) & 1u);
}
__device__ __forceinline__ unsigned short f2bf(float f) {
  unsigned u = __builtin_bit_cast(unsigned, f);
  return (unsigned short)(rnd_bf(u) >> 16);
}

#define GLDS16(gp, lp)                                                         \
  __builtin_amdgcn_global_load_lds(                                            \
      (const __attribute__((address_space(1))) unsigned*)(const void*)(gp),    \
      (__attribute__((address_space(3))) unsigned*)(lp), 16, 0, 0)

// ---------------- cast x f32 -> bf16 ----------------
__global__ void cast_x_kernel(const float* __restrict__ x, unsigned short* __restrict__ xb) {
  const size_t i = ((size_t)blockIdx.x * 256 + threadIdx.x) * 4;
  float4 v = *(const float4*)(x + i);
  ushort4 o;
  o.x = f2bf(v.x); o.y = f2bf(v.y); o.z = f2bf(v.z); o.w = f2bf(v.w);
  *(ushort4*)(xb + i) = o;
}

// ---------------- router ----------------
__global__ void router_kernel(const float* __restrict__ x, const float* __restrict__ wg,
                              float* __restrict__ logits_out, int* __restrict__ topi,
                              float* __restrict__ topv, int* __restrict__ counts) {
  const int wave = threadIdx.x >> 6, lane = threadIdx.x & 63;
  const int t = blockIdx.x * 4 + wave;
  const float* xr = x + (size_t)t * HD;
  float acc[8];
#pragma unroll
  for (int e = 0; e < 8; ++e) acc[e] = 0.f;
  for (int d = lane; d < HD; d += 64) {
    const float xv = xr[d];
    const float4 w0 = *(const float4*)(wg + (size_t)d * 8);
    const float4 w1 = *(const float4*)(wg + (size_t)d * 8 + 4);
    acc[0] += xv * w0.x; acc[1] += xv * w0.y; acc[2] += xv * w0.z; acc[3] += xv * w0.w;
    acc[4] += xv * w1.x; acc[5] += xv * w1.y; acc[6] += xv * w1.z; acc[7] += xv * w1.w;
  }
#pragma unroll
  for (int e = 0; e < 8; ++e) {
#pragma unroll
    for (int off = 32; off > 0; off >>= 1) acc[e] += __shfl_xor(acc[e], off);
  }
  if (lane == 0) {
    *(float4*)(logits_out + (size_t)t * 8)     = make_float4(acc[0], acc[1], acc[2], acc[3]);
    *(float4*)(logits_out + (size_t)t * 8 + 4) = make_float4(acc[4], acc[5], acc[6], acc[7]);
    float mx = acc[0];
#pragma unroll
    for (int e = 1; e < 8; ++e) mx = fmaxf(mx, acc[e]);
    float p[8], s = 0.f;
#pragma unroll
    for (int e = 0; e < 8; ++e) { p[e] = expf(acc[e] - mx); s += p[e]; }
    const float inv = 1.f / s;
    int i1 = 0;
#pragma unroll
    for (int e = 1; e < 8; ++e) if (acc[e] > acc[i1]) i1 = e;
    int i2 = (i1 == 0) ? 1 : 0;
#pragma unroll
    for (int e = 0; e < 8; ++e) if (e != i1 && acc[e] > acc[i2]) i2 = e;
    topi[2 * t]     = i1; topv[2 * t]     = p[i1] * inv;
    topi[2 * t + 1] = i2; topv[2 * t + 1] = p[i2] * inv;
    atomicAdd(&counts[i1], 1);
    atomicAdd(&counts[i2], 1);
  }
}

__global__ void offs_kernel(const int* __restrict__ counts, int* __restrict__ offs,
                            int* __restrict__ cursors) {
  if (threadIdx.x == 0) {
    int r = 0;
    for (int e = 0; e < NE; ++e) { offs[e] = r; cursors[e] = r; r += counts[e]; }
  }
}

__global__ void gather_kernel(const unsigned short* __restrict__ xb,
                              const int* __restrict__ topi, const float* __restrict__ topv,
                              int* __restrict__ cursors, unsigned short* __restrict__ xg,
                              int* __restrict__ row_token, float* __restrict__ row_gate) {
  const int wave = threadIdx.x >> 6, lane = threadIdx.x & 63;
  const int t = blockIdx.x * 4 + wave;
  const uint4* src = (const uint4*)(xb + (size_t)t * HD);
#pragma unroll
  for (int j = 0; j < 2; ++j) {
    const int e = topi[2 * t + j];
    int pos = 0;
    if (lane == 0) {
      pos = atomicAdd(&cursors[e], 1);
      row_token[pos] = t;
      row_gate[pos] = topv[2 * t + j];
    }
    pos = __shfl(pos, 0);
    uint4* dst = (uint4*)(xg + (size_t)pos * HD);
#pragma unroll
    for (int c = lane; c < 256; c += 64) dst[c] = src[c];
  }
}

// ---------------- pack: f32 [K][N] -> bf16 B^T [N][K] ----------------
template <int K, int N>
__global__ __launch_bounds__(256) void pack_wt(const float* __restrict__ we,
                                               const float* __restrict__ ws,
                                               unsigned short* __restrict__ dstw) {
  const int e = blockIdx.z;
  const float* src = (e < NE) ? (we + (size_t)e * K * N) : (ws + (size_t)(e - NE) * K * N);
  unsigned short* dst = dstw + (size_t)e * K * N;
  const int nt = blockIdx.x * 64;
  const int kt = blockIdx.y * 64;
  __shared__ unsigned short t[64][73];
  const int tid = threadIdx.x;
  const int rr = tid >> 4, cc = (tid & 15) * 4;
#pragma unroll
  for (int i = 0; i < 4; ++i) {
    const int k = rr + i * 16;
    float4 v = *(const float4*)(src + (size_t)(kt + k) * N + nt + cc);
    t[k][cc + 0] = f2bf(v.x);
    t[k][cc + 1] = f2bf(v.y);
    t[k][cc + 2] = f2bf(v.z);
    t[k][cc + 3] = f2bf(v.w);
  }
  __syncthreads();
  const int nr = tid >> 2, kc = (tid & 3) * 16;
  unsigned u[8];
#pragma unroll
  for (int j = 0; j < 8; ++j)
    u[j] = (unsigned)t[kc + 2 * j][nr] | ((unsigned)t[kc + 2 * j + 1][nr] << 16);
  unsigned short* dp = dst + (size_t)(nt + nr) * K + kt + kc;
  uint4 v0; v0.x = u[0]; v0.y = u[1]; v0.z = u[2]; v0.w = u[3];
  uint4 v1; v1.x = u[4]; v1.y = u[5]; v1.z = u[6]; v1.w = u[7];
  *(uint4*)dp = v0;
  *(uint4*)(dp + 8) = v1;
}

// ---------------- frag read / mfma helpers (all static after inline) ----------
template <int MS>
__device__ __forceinline__ void rd_a(bf16x8 (&d)[8], const unsigned short* base,
                                     int wr, int fr, int fq, int swz) {
#pragma unroll
  for (int mi = 0; mi < 4; ++mi)
#pragma unroll
    for (int ks = 0; ks < 2; ++ks)
      d[mi * 2 + ks] = *(const bf16x8*)(base + (wr * 128 + MS * 64 + mi * 16 + fr) * 64 +
                                        (((ks * 4 + fq) ^ swz) << 3));
}
template <int NSUB>
__device__ __forceinline__ void rd_b(bf16x8 (&d)[4], const unsigned short* base,
                                     int wc, int fr, int fq, int swz) {
#pragma unroll
  for (int ni = 0; ni < 2; ++ni)
#pragma unroll
    for (int ks = 0; ks < 2; ++ks)
      d[ni * 2 + ks] = *(const bf16x8*)(base + (wc * 64 + NSUB * 32 + ni * 16 + fr) * 64 +
                                        (((ks * 4 + fq) ^ swz) << 3));
}
template <int MS, int NSUB>
__device__ __forceinline__ void mm16(f32x4 (&acc)[8][4], const bf16x8 (&a)[8],
                                     const bf16x8 (&b)[4]) {
  __builtin_amdgcn_s_setprio(1);
#pragma unroll
  for (int mi = 0; mi < 4; ++mi)
#pragma unroll
    for (int ni = 0; ni < 2; ++ni)
#pragma unroll
      for (int ks = 0; ks < 2; ++ks)
        acc[MS * 4 + mi][NSUB * 2 + ni] = __builtin_amdgcn_mfma_f32_16x16x32_bf16(
            a[mi * 2 + ks], b[ni * 2 + ks], acc[MS * 4 + mi][NSUB * 2 + ni], 0, 0, 0);
  __builtin_amdgcn_s_setprio(0);
}

// ---------------- 256x256 8-phase grouped GEMM ----------------
// BM=BN=256, BK=64, 512 thr (8 waves 2x4), dbuf LDS 128 KiB, counted vmcnt(4)
// per K-tile, raw s_barrier, setprio around MFMA clusters, both-sides XOR
// swizzle, m-fast chunked XCD map.
// MODE 0: h = relu(A[M x 2048] * W1t^T + b1) -> bf16 hbuf
// MODE 1: out[token] += gate * (A[M x 8192] * W2t^T + b2)  (atomic f32)
template <int MODE>
__global__ __launch_bounds__(512, 2) void gemm8p(
    const unsigned short* __restrict__ Ash,   // MODE0: xb, MODE1: hbuf
    const unsigned short* __restrict__ Art,   // MODE0: xg, MODE1: hbuf
    const unsigned short* __restrict__ wt,    // packed B^T [10][N*K]
    const float* __restrict__ bE, const float* __restrict__ bS,
    unsigned short* __restrict__ hout, float* __restrict__ out,
    const int* __restrict__ counts, const int* __restrict__ offs,
    const int* __restrict__ row_token, const float* __restrict__ row_gate) {
  constexpr int K = (MODE == 0) ? HD : FF;
  constexpr int N = (MODE == 0) ? FF : HD;
  constexpr int NBX = N / 256;          // 32 or 8
  constexpr int NWG = NBX * 16;         // xy blocks per expert (%8==0)
  extern __shared__ unsigned short smem[];  // [2][A 16384 | B 16384] ushorts

  const int e = blockIdx.z;
  int M;
  const unsigned short* A;
  const float* bias;
  int hbase = 0;
  const int* tok = nullptr;
  const float* gt = nullptr;

  if (e < NE) {
    M = counts[e];
    const int off = offs[e];
    A = Art + (size_t)off * K;
    if (MODE == 1) { tok = row_token + off; gt = row_gate + off; }
    bias = bE + (size_t)e * N;
    hbase = off;
  } else {
    M = TOKENS;
    const int se = e - NE;
    hbase = 2 * TOKENS + se * TOKENS;
    if (MODE == 0) A = Ash;
    else           A = Ash + (size_t)hbase * K;
    bias = bS + (size_t)se * N;
  }
  const unsigned short* Bt = wt + (size_t)e * HD * FF;  // [N][K]

  // chunked XCD swizzle, m-fast (period 16 divides chunk): uniform validity.
  int flat = blockIdx.x + NBX * blockIdx.y;
  flat = (flat & 7) * (NWG >> 3) + (flat >> 3);
  const int m0 = (flat & 15) * 256;
  const int n0 = (flat >> 4) * 256;
  if (m0 >= M) return;

  const int tid = threadIdx.x;
  const int wid = tid >> 6, ln = tid & 63;
  const int wr = wid >> 2, wc = wid & 3;
  const int fr = ln & 15, fq = ln >> 4;
  const int swz = fr & 7;

  // staging decomposition: 512 thr x 2 loads = 128 rows x 8 octets per half
  const int srr = tid >> 3;                    // 0..63 (j=0 row; j=1 adds 64)
  const int soct = tid & 7;
  const int scol = (soct ^ (srr & 7)) << 3;    // pre-swizzled global col (elems)

#define STAGE_A(h, kt, b)                                                      \
  { const unsigned short* s_ = A + (size_t)(m0 + (h) * 128 + srr) * K + (kt) * 64 + scol; \
    unsigned short* d_ = smem + (b) * 32768 + ((h) * 128 + srr) * 64 + soct * 8; \
    GLDS16(s_, d_); GLDS16(s_ + (size_t)64 * K, d_ + 4096); }
#define STAGE_B(h, kt, b)                                                      \
  { const unsigned short* s_ = Bt + (size_t)(n0 + (h) * 128 + srr) * K + (kt) * 64 + scol; \
    unsigned short* d_ = smem + (b) * 32768 + 16384 + ((h) * 128 + srr) * 64 + soct * 8; \
    GLDS16(s_, d_); GLDS16(s_ + (size_t)64 * K, d_ + 4096); }

  f32x4 acc[8][4];
#pragma unroll
  for (int i = 0; i < 8; ++i)
#pragma unroll
    for (int j = 0; j < 4; ++j) acc[i][j] = (f32x4){0.f, 0.f, 0.f, 0.f};

  // prologue: full tile0 -> buf0; B0,A0 of tile1 -> buf1; allow last 2 halves
  // (4 loads) in flight.
  STAGE_A(0, 0, 0); STAGE_B(0, 0, 0); STAGE_A(1, 0, 0); STAGE_B(1, 0, 0);
  STAGE_B(0, 1, 1); STAGE_A(0, 1, 1);
  asm volatile("s_waitcnt vmcnt(4)" ::: "memory");
  __builtin_amdgcn_s_barrier();

  bf16x8 a0[8], a1[8], b0[4], b1[4];
  const int nkt = K / 64;
  int cur = 0;
  for (int t = 0; t < nkt; ++t) {
    const int nxt = cur ^ 1;
    const int tp1 = (t + 1 < nkt) ? t + 1 : t;   // clamped redundant re-stage
    const int tp2 = (t + 2 < nkt) ? t + 2 : t;
    const unsigned short* As_c = smem + cur * 32768;
    const unsigned short* Bs_c = As_c + 16384;
    // ---- ph1: Q(m0,n0) ----
    rd_a<0>(a0, As_c, wr, fr, fq, swz);
    rd_b<0>(b0, Bs_c, wc, fr, fq, swz);
    STAGE_A(1, tp1, nxt);
    __builtin_amdgcn_s_barrier();
    mm16<0, 0>(acc, a0, b0);
    __builtin_amdgcn_s_barrier();
    // ---- ph2: Q(m0,n1) ----
    rd_b<1>(b1, Bs_c, wc, fr, fq, swz);
    STAGE_B(1, tp1, nxt);
    __builtin_amdgcn_s_barrier();
    mm16<0, 1>(acc, a0, b1);
    __builtin_amdgcn_s_barrier();
    // ---- ph3: Q(m1,n1) ---- (all B reads of cur done after ph2 -> B0 of t+2
    // may overwrite cur.B0)
    rd_a<1>(a1, As_c, wr, fr, fq, swz);
    STAGE_B(0, tp2, cur);
    __builtin_amdgcn_s_barrier();
    mm16<1, 1>(acc, a1, b1);
    __builtin_amdgcn_s_barrier();
    // ---- ph4: Q(m1,n0) ---- (all A reads of cur done after ph3)
    STAGE_A(0, tp2, cur);
    __builtin_amdgcn_s_barrier();
    mm16<1, 0>(acc, a1, b0);
    // counted drain: newest 4 loads (B0,A0 of t+2) may stay in flight;
    // A1,B1 of t+1 and older are guaranteed landed.
    asm volatile("s_waitcnt vmcnt(4)" ::: "memory");
    __builtin_amdgcn_s_barrier();
    cur = nxt;
  }
#undef STAGE_A
#undef STAGE_B

  if (MODE == 0) {
#pragma unroll
    for (int nn = 0; nn < 4; ++nn) {
      const int col = n0 + wc * 64 + (nn >> 1) * 32 + (nn & 1) * 16 + fr;
      const float bb = bias[col];
#pragma unroll
      for (int mm = 0; mm < 8; ++mm) {
#pragma unroll
        for (int j = 0; j < 4; ++j) {
          const int r = m0 + wr * 128 + (mm >> 2) * 64 + (mm & 3) * 16 + fq * 4 + j;
          if (r < M) {
            float v = acc[mm][nn][j] + bb;
            v = v > 0.f ? v : 0.f;
            hout[(size_t)(hbase + r) * FF + col] = f2bf(v);
          }
        }
      }
    }
  } else {
#pragma unroll
    for (int mm = 0; mm < 8; ++mm) {
#pragma unroll
      for (int j = 0; j < 4; ++j) {
        const int r = m0 + wr * 128 + (mm >> 2) * 64 + (mm & 3) * 16 + fq * 4 + j;
        if (r < M) {
          const int t = tok ? tok[r] : r;
          const float g = gt ? gt[r] : 1.f;
          float* orow = out + (size_t)t * HD + n0;
#pragma unroll
          for (int nn = 0; nn < 4; ++nn) {
            const int col = wc * 64 + (nn >> 1) * 32 + (nn & 1) * 16 + fr;
            atomicAdd(orow + col, g * (acc[mm][nn][j] + bias[n0 + col]));
          }
        }
      }
    }
  }
}

extern "C" void kernel_launch(void* const* d_in, const int* in_sizes, int n_in,
                              void* d_out, int out_size, void* d_ws, size_t ws_size,
                              hipStream_t stream) {
  const float* x     = (const float*)d_in[0];
  const float* ws_w1 = (const float*)d_in[1];
  const float* ws_b1 = (const float*)d_in[2];
  const float* ws_w2 = (const float*)d_in[3];
  const float* ws_b2 = (const float*)d_in[4];
  const float* we_w1 = (const float*)d_in[5];
  const float* we_b1 = (const float*)d_in[6];
  const float* we_w2 = (const float*)d_in[7];
  const float* we_b2 = (const float*)d_in[8];
  const float* wg    = (const float*)d_in[9];

  float* out = (float*)d_out;
  float* logits = out + (size_t)TOKENS * HD;

  // layout: wt | xb | xg | hbuf | ctrl  (xg before hbuf so 256-tile A-overruns
  // of the last routed expert land inside hbuf, not past the workspace)
  char* ws = (char*)d_ws;
  unsigned short* wt   = (unsigned short*)ws;                   // 335,544,320 B
  unsigned short* xb   = (unsigned short*)(ws + 335544320);     //  16,777,216 B
  unsigned short* xg   = (unsigned short*)(ws + 352321536);     //  34,078,720 B
  unsigned short* hbuf = (unsigned short*)(ws + 386400256);     // 268,435,456 B
  char* ctrl = ws + 654835712;
  int*   row_token = (int*)(ctrl);
  float* row_gate  = (float*)(ctrl + 32768);
  int*   topi      = (int*)(ctrl + 65536);
  float* topv      = (float*)(ctrl + 98304);
  int*   counts    = (int*)(ctrl + 131072);
  int*   offs      = (int*)(ctrl + 131104);
  int*   cursors   = (int*)(ctrl + 131136);

  hipFuncSetAttribute(reinterpret_cast<const void*>(gemm8p<0>),
                      hipFuncAttributeMaxDynamicSharedMemorySize, 131072);
  hipFuncSetAttribute(reinterpret_cast<const void*>(gemm8p<1>),
                      hipFuncAttributeMaxDynamicSharedMemorySize, 131072);

  hipMemsetAsync(out, 0, (size_t)TOKENS * HD * sizeof(float), stream);
  hipMemsetAsync(counts, 0, NE * sizeof(int), stream);

  cast_x_kernel<<<8192, 256, 0, stream>>>(x, xb);
  router_kernel<<<1024, 256, 0, stream>>>(x, wg, logits, topi, topv, counts);
  offs_kernel<<<1, 64, 0, stream>>>(counts, offs, cursors);
  gather_kernel<<<1024, 256, 0, stream>>>(xb, topi, topv, cursors, xg, row_token, row_gate);

  // pack W1 [10][2048][8192] f32 -> [10][8192][2048] bf16
  pack_wt<HD, FF><<<dim3(FF / 64, HD / 64, 10), 256, 0, stream>>>(we_w1, ws_w1, wt);
  // GEMM1: h = relu(x*W1+b1)   (N=8192 -> 32 n-blocks, 16 m-blocks, 10 experts)
  gemm8p<0><<<dim3(32, 16, 10), 512, 131072, stream>>>(
      xb, xg, wt, we_b1, ws_b1, hbuf, nullptr, counts, offs, nullptr, nullptr);
  // pack W2 [10][8192][2048] f32 -> [10][2048][8192] bf16 (reuses wt)
  pack_wt<FF, HD><<<dim3(HD / 64, FF / 64, 10), 256, 0, stream>>>(we_w2, ws_w2, wt);
  // GEMM2: out += gate*(h*W2+b2)  (N=2048 -> 8 n-blocks)
  gemm8p<1><<<dim3(8, 16, 10), 512, 131072, stream>>>(
      hbuf, hbuf, wt, we_b2, ws_b2, nullptr, out, counts, offs, row_token, row_gate);

  (void)in_sizes; (void)n_in; (void)out_size; (void)ws_size;
}